// Round 10
// baseline (421.325 us; speedup 1.0000x reference)
//
#include <hip/hip_runtime.h>

#define DI __device__ __forceinline__

typedef float  f32x2  __attribute__((ext_vector_type(2)));
typedef float  f32x4  __attribute__((ext_vector_type(4)));
typedef float  f32x16 __attribute__((ext_vector_type(16)));
typedef __bf16 bf16x8 __attribute__((ext_vector_type(8)));
typedef unsigned u32x2 __attribute__((ext_vector_type(2)));
typedef unsigned u32x4 __attribute__((ext_vector_type(4)));

static constexpr int TB   = 2048;   // tokens per batch
static constexpr int NTOK = 8192;   // 4 * 2048
static constexpr int EMB  = 1024;
static constexpr int FQKV = 3072;

// RTNE float -> bf16 bits
DI unsigned short f2bf(float f) {
  union { float f; unsigned u; } v; v.f = f;
  unsigned r = v.u + 0x7FFFu + ((v.u >> 16) & 1u);
  return (unsigned short)(r >> 16);
}

DI unsigned pack2bf(float a, float b) {
#if __has_builtin(__builtin_amdgcn_cvt_pk_bf16_f32)
  typedef __bf16 bf16x2 __attribute__((ext_vector_type(2)));
  bf16x2 r = __builtin_amdgcn_cvt_pk_bf16_f32(a, b);
  return __builtin_bit_cast(unsigned, r);
#else
  unsigned ua = __builtin_bit_cast(unsigned, a) + 0x8000u;
  unsigned ub = __builtin_bit_cast(unsigned, b) + 0x8000u;
  return __builtin_amdgcn_perm(ub, ua, 0x07060302u);
#endif
}

DI void plswap(unsigned& a, unsigned& b) {
#if __has_builtin(__builtin_amdgcn_permlane32_swap)
  u32x2 r = __builtin_amdgcn_permlane32_swap(a, b, false, false);
  a = r.x; b = r.y;
#else
  const bool hi = (threadIdx.x & 32) != 0;
  unsigned ax = (unsigned)__shfl_xor((int)a, 32);
  unsigned bx = (unsigned)__shfl_xor((int)b, 32);
  unsigned na = hi ? bx : a;
  unsigned nb = hi ? b : ax;
  a = na; b = nb;
#endif
}

DI bf16x8 frag4(unsigned a, unsigned b, unsigned c, unsigned d) {
  u32x4 u = {a, b, c, d};
  return __builtin_bit_cast(bf16x8, u);
}

// async global->LDS, 16B per lane; LDS dest = wave-uniform base + lane*16
DI void gload16(const void* g, void* l) {
  __builtin_amdgcn_global_load_lds(
      (__attribute__((address_space(1))) void*)(g),
      (__attribute__((address_space(3))) void*)(l), 16, 0, 0);
}

DI void wait_vm2() { asm volatile("s_waitcnt vmcnt(2)" ::: "memory"); }
DI void wait_vm0() { asm volatile("s_waitcnt vmcnt(0)" ::: "memory"); }
DI void rbar()     { __builtin_amdgcn_s_barrier(); }
DI void sfence()   { __builtin_amdgcn_sched_barrier(0); }

// barrier with guaranteed pre-drain of this wave's outstanding DMA ops
DI void syncdrain() {
  __builtin_amdgcn_s_waitcnt(0);
  __syncthreads();
}

// ---------------- fp32 -> bf16 conversion for x, w_qkv, w_out ----------------
__global__ __launch_bounds__(256)
void cvt_kernel(const float4* __restrict__ x, const float4* __restrict__ wq,
                const float4* __restrict__ wo,
                ushort4* __restrict__ xb, ushort4* __restrict__ wqb,
                ushort4* __restrict__ wob) {
  const int nx   = NTOK * EMB / 4;
  const int nq   = FQKV * EMB / 4;
  const int ntot = nx + nq + EMB * EMB / 4;
  for (int i = blockIdx.x * 256 + threadIdx.x; i < ntot; i += gridDim.x * 256) {
    float4 v; ushort4* dst;
    if (i < nx)           { v = x[i];            dst = xb  + i; }
    else if (i < nx + nq) { v = wq[i - nx];      dst = wqb + (i - nx); }
    else                  { v = wo[i - nx - nq]; dst = wob + (i - nx - nq); }
    ushort4 p;
    p.x = f2bf(v.x); p.y = f2bf(v.y); p.z = f2bf(v.z); p.w = f2bf(v.w);
    *dst = p;
  }
}

// ---------------- 256x128 bf16 QKV GEMM (reverted to r7/r8: best measured) ---
// r9 closed the GEMM-restructure chapter: the faithful 8-phase template ran
// at 119us (MfmaUtil 16, occ 16%) — with K=1024 there are only 16 K-tiles to
// amortize its 8-barrier-per-tile lockstep, vs m201's 64+ at 4096^3. Every
// 1-block/CU variant (r2,r3,r4,r5,r9) lost to this flat multi-block kernel.
__global__ __launch_bounds__(512, 4)
void gemm_qkv(const unsigned short* __restrict__ A,
              const unsigned short* __restrict__ Bt,
              const int K,
              unsigned short* __restrict__ qk,
              unsigned short* __restrict__ vT) {
  __shared__ unsigned short sA[256 * 32];   // 16KB
  __shared__ unsigned short sB[128 * 32];   // 8KB
  const int tid  = threadIdx.x;
  const int w    = tid >> 6;          // 0..7
  const int l    = tid & 63;
  const int quad = l >> 4;
  const int lr   = l & 15;
  const int nwg  = gridDim.x * gridDim.y;
  const int orig = blockIdx.y * gridDim.x + blockIdx.x;
  const int swzb = (orig & 7) * (nwg >> 3) + (orig >> 3);
  const int n0   = (swzb % gridDim.x) * 128;
  const int m0   = (swzb / gridDim.x) * 256;
  const int wm   = (w >> 1) * 64;
  const int wn   = (w & 1) * 64;

  f32x4 acc[4][4];
#pragma unroll
  for (int i = 0; i < 4; ++i)
#pragma unroll
    for (int j = 0; j < 4; ++j) acc[i][j] = {0.f, 0.f, 0.f, 0.f};

  const int srow = l >> 2;
  const int sg   = (l & 3) ^ ((l >> 3) & 3);
  const unsigned short* gA = A  + (long)(m0 + w * 32 + srow) * K + sg * 8;
  const unsigned short* gB = Bt + (long)(n0 + w * 16 + srow) * K + sg * 8;
  unsigned short* lA = sA + w * 1024;
  unsigned short* lB = sB + w * 512;
  const int swz = (lr >> 1) & 3;

  for (int k0 = 0; k0 < K; k0 += 32) {
    gload16(gA + k0,          lA);
    gload16(gA + k0 + 16 * K, lA + 512);
    gload16(gB + k0,          lB);
    syncdrain();
    bf16x8 af[4], bfr[4];
#pragma unroll
    for (int rt = 0; rt < 4; ++rt)
      af[rt] = *(const bf16x8*)(sA + (wm + rt * 16 + lr) * 32 + (quad ^ swz) * 8);
#pragma unroll
    for (int ct = 0; ct < 4; ++ct)
      bfr[ct] = *(const bf16x8*)(sB + (wn + ct * 16 + lr) * 32 + (quad ^ swz) * 8);
#pragma unroll
    for (int rt = 0; rt < 4; ++rt)
#pragma unroll
      for (int ct = 0; ct < 4; ++ct)
        acc[rt][ct] = __builtin_amdgcn_mfma_f32_16x16x32_bf16(af[rt], bfr[ct],
                                                              acc[rt][ct], 0, 0, 0);
    __syncthreads();
  }

  if (n0 < 2048) {
    const float qs = (n0 < 1024) ? 0.18033688011112042f : 1.0f;
#pragma unroll
    for (int rt = 0; rt < 4; ++rt) {
      const int row = m0 + wm + rt * 16 + quad * 4;
#pragma unroll
      for (int ct = 0; ct < 4; ++ct) {
        const int col = n0 + wn + ct * 16 + lr;
#pragma unroll
        for (int r = 0; r < 4; ++r)
          qk[(long)(row + r) * 2048 + col] = f2bf(acc[rt][ct][r] * qs);
      }
    }
  } else {
#pragma unroll
    for (int rt = 0; rt < 4; ++rt) {
      const int tok = m0 + wm + rt * 16 + quad * 4;
      const int bb  = tok >> 11, tt = tok & 2047;
#pragma unroll
      for (int ct = 0; ct < 4; ++ct) {
        const int fv = n0 - 2048 + wn + ct * 16 + lr;  // h*64+d
        ushort4 p;
        p.x = f2bf(acc[rt][ct][0]); p.y = f2bf(acc[rt][ct][1]);
        p.z = f2bf(acc[rt][ct][2]); p.w = f2bf(acc[rt][ct][3]);
        *(ushort4*)(vT + ((long)(bb * 1024 + fv)) * 2048 + tt) = p;
      }
    }
  }
}

// ---------------- 128x64 bf16 out-projection GEMM (frozen from r8) ----------
__global__ __launch_bounds__(256, 4)
void gemm_out(const unsigned short* __restrict__ A,
              const unsigned short* __restrict__ Bt,
              const int K,
              float* __restrict__ outp) {
  __shared__ unsigned short sA[128 * 32];   // 8KB
  __shared__ unsigned short sB[64 * 32];    // 4KB
  const int tid  = threadIdx.x;
  const int w    = tid >> 6;
  const int l    = tid & 63;
  const int quad = l >> 4;
  const int lr   = l & 15;
  const int nwg  = gridDim.x * gridDim.y;   // 1024, %8==0
  const int orig = blockIdx.y * gridDim.x + blockIdx.x;
  const int swzb = (orig & 7) * (nwg >> 3) + (orig >> 3);
  const int n0   = (swzb % gridDim.x) * 64;
  const int m0   = (swzb / gridDim.x) * 128;
  const int wm   = (w >> 1) * 64;
  const int wn   = (w & 1) * 32;

  f32x4 acc[4][2];
#pragma unroll
  for (int i = 0; i < 4; ++i)
#pragma unroll
    for (int j = 0; j < 2; ++j) acc[i][j] = {0.f, 0.f, 0.f, 0.f};

  const int srow = l >> 2;
  const int sg   = (l & 3) ^ ((l >> 3) & 3);
  const unsigned short* gA = A  + (long)(m0 + w * 32 + srow) * K + sg * 8;
  const unsigned short* gB = Bt + (long)(n0 + w * 16 + srow) * K + sg * 8;
  unsigned short* lA = sA + w * 1024;
  unsigned short* lB = sB + w * 512;
  const int swz = (lr >> 1) & 3;

  for (int k0 = 0; k0 < K; k0 += 32) {
    gload16(gA + k0,          lA);
    gload16(gA + k0 + 16 * K, lA + 512);
    gload16(gB + k0,          lB);
    syncdrain();
    bf16x8 af[4], bfr[2];
#pragma unroll
    for (int rt = 0; rt < 4; ++rt)
      af[rt] = *(const bf16x8*)(sA + (wm + rt * 16 + lr) * 32 + (quad ^ swz) * 8);
#pragma unroll
    for (int ct = 0; ct < 2; ++ct)
      bfr[ct] = *(const bf16x8*)(sB + (wn + ct * 16 + lr) * 32 + (quad ^ swz) * 8);
#pragma unroll
    for (int rt = 0; rt < 4; ++rt)
#pragma unroll
      for (int ct = 0; ct < 2; ++ct)
        acc[rt][ct] = __builtin_amdgcn_mfma_f32_16x16x32_bf16(af[rt], bfr[ct],
                                                              acc[rt][ct], 0, 0, 0);
    __syncthreads();
  }

#pragma unroll
  for (int rt = 0; rt < 4; ++rt) {
    const int row = m0 + wm + rt * 16 + quad * 4;
#pragma unroll
    for (int ct = 0; ct < 2; ++ct) {
      const int col = n0 + wn + ct * 16 + lr;
#pragma unroll
      for (int r = 0; r < 4; ++r)
        outp[(long)(row + r) * 1024 + col] = acc[rt][ct][r];
    }
  }
}

// ---------------- flash attention v8: V direct from L2 -----------------------
// r10: attn counters stable across r2-r9 (91us, MfmaUtil 33, VALU 50, occ 32%,
// conflicts 8.4M). No pipe saturated -> raise TLP and cut LDS pressure.
// Mechanism (catalog common-mistake #7 / m169, +26% measured): K/V per (b,h)
// is 512KB; 8 bh per XCD = 4MB = exactly one L2 — V staging is overhead.
// V frags become direct per-lane 16B global reads (vT is [bh][d][t], so the
// old swizzled-LDS read reduces to vb + t*64 + (G*2+sub)*16; stage/read XORs
// cancel — verified algebraically). Effects: LDS 32->16KB, staging 4->2
// loads/tile (vmcnt(2)), V-side bank conflicts vanish, launch_bounds(256,6)
// lets up to 8 blocks/CU co-reside (VGPR ~52-60).
__global__ __launch_bounds__(256, 6)
void attn_kernel(const unsigned short* __restrict__ qk,
                 const unsigned short* __restrict__ vT,
                 unsigned short* __restrict__ attnb) {
  __shared__ unsigned short sK[2][64 * 64];   // 16KB total
  const int tid = threadIdx.x;
  const int w   = tid >> 6;
  const int l   = tid & 63;
  const int l31 = l & 31;
  const int lh  = l >> 5;
  const int h8  = lh * 8;
  const int bh  = blockIdx.x;
  const int hh  = bh & 15;
  const long tokbase = (long)(bh >> 4) * TB;
  const int qbase = blockIdx.y * 128 + w * 32;

  bf16x8 qf[4];
  {
    const unsigned short* qptr = qk + (tokbase + qbase + l31) * 2048 + hh * 64 + h8;
#pragma unroll
    for (int s = 0; s < 4; ++s) qf[s] = *(const bf16x8*)(qptr + s * 16);
  }

  // K staging (unchanged geometry, K only)
  const int srow = l >> 3;
  const int g    = (l & 7) ^ srow;
  const unsigned short* kbase =
      qk + (tokbase + w * 16 + srow) * 2048 + 1024 + hh * 64 + g * 8;
  // V: per-lane direct global bases (rows d=l31 and d=32+l31 of this bh)
  const unsigned short* vb0 = vT + ((long)bh * 64 + l31) * 2048 + lh * 8;
  const unsigned short* vb1 = vb0 + 32 * 2048;

  f32x16 oacc[2] = {{}, {}};
  f32x2 lp2 = {0.f, 0.f};

  gload16(kbase,            &sK[0][(w * 16 + 0) * 64]);
  gload16(kbase + 8 * 2048, &sK[0][(w * 16 + 8) * 64]);

  for (int t = 0; t < 32; ++t) {
    const int buf = t & 1;
    if (t + 1 < 32) {
      const long k0 = (long)(t + 1) * 64;
      const int nb = buf ^ 1;
      gload16(kbase + k0 * 2048,            &sK[nb][(w * 16 + 0) * 64]);
      gload16(kbase + k0 * 2048 + 8 * 2048, &sK[nb][(w * 16 + 8) * 64]);
      wait_vm2();   // tile t's 2 K-stages landed; t+1's 2 stay in flight
    } else {
      wait_vm0();
    }
    sfence();
    rbar();
    sfence();
    const unsigned short* bK = sK[buf];

#pragma unroll
    for (int G = 0; G < 2; ++G) {
      f32x16 sacc = {};
      __builtin_amdgcn_s_setprio(1);
#pragma unroll
      for (int s = 0; s < 4; ++s) {
        const int key = G * 32 + l31;
        const int p   = (s * 2 + lh) ^ (key & 7);
        const bf16x8 kf = *(const bf16x8*)(bK + key * 64 + p * 8);
        sacc = __builtin_amdgcn_mfma_f32_32x32x16_bf16(kf, qf[s], sacc, 0, 0, 0);
      }
      __builtin_amdgcn_s_setprio(0);
      float e[16];
#pragma unroll
      for (int i = 0; i < 16; ++i) e[i] = __builtin_amdgcn_exp2f(sacc[i]);
#pragma unroll
      for (int i = 0; i < 8; ++i) {
        f32x2 pr = {e[2 * i], e[2 * i + 1]};
        lp2 += pr;
      }
      unsigned d[8];
#pragma unroll
      for (int i = 0; i < 8; ++i) d[i] = pack2bf(e[2 * i], e[2 * i + 1]);
      plswap(d[0], d[2]); plswap(d[1], d[3]);
      plswap(d[4], d[6]); plswap(d[5], d[7]);
      bf16x8 pp[2];
      pp[0] = frag4(d[0], d[1], d[2], d[3]);
      pp[1] = frag4(d[4], d[5], d[6], d[7]);
      // O += P V: V frags direct from global (L2-resident)
      __builtin_amdgcn_s_setprio(1);
#pragma unroll
      for (int sub = 0; sub < 2; ++sub) {
        const int co = t * 64 + (G * 2 + sub) * 16;   // element offset
        const bf16x8 vf0 = *(const bf16x8*)(vb0 + co);
        const bf16x8 vf1 = *(const bf16x8*)(vb1 + co);
        oacc[0] = __builtin_amdgcn_mfma_f32_32x32x16_bf16(pp[sub], vf0, oacc[0], 0, 0, 0);
        oacc[1] = __builtin_amdgcn_mfma_f32_32x32x16_bf16(pp[sub], vf1, oacc[1], 0, 0, 0);
      }
      __builtin_amdgcn_s_setprio(0);
    }
    sfence();
    rbar();
  }

  const float lp = lp2.x + lp2.y;
  const float fs = lp + __shfl_xor(lp, 32);
  const float rc = 1.0f / fs;
#pragma unroll
  for (int r = 0; r < 16; ++r) {
    const int row = (r & 3) + 8 * (r >> 2) + 4 * lh;
    const float sc = __shfl(rc, row);
    const long base = (tokbase + qbase + row) * 1024 + hh * 64;
    attnb[base + l31]      = f2bf(oacc[0][r] * sc);
    attnb[base + 32 + l31] = f2bf(oacc[1][r] * sc);
  }
}

// ---------------------------------------------------------------------------
extern "C" void kernel_launch(void* const* d_in, const int* in_sizes, int n_in,
                              void* d_out, int out_size, void* d_ws, size_t ws_size,
                              hipStream_t stream) {
  const float* x    = (const float*)d_in[0];
  const float* wqkv = (const float*)d_in[1];
  const float* wout = (const float*)d_in[2];
  float* outp = (float*)d_out;

  unsigned short* xb    = (unsigned short*)d_ws;          // 8192*1024
  unsigned short* wqkvb = xb    + (long)NTOK * EMB;       // 3072*1024
  unsigned short* woutb = wqkvb + (long)FQKV * EMB;       // 1024*1024
  unsigned short* qkb   = woutb + (long)EMB * EMB;        // 8192*2048 (Q|K)
  unsigned short* vTb   = qkb   + (long)NTOK * 2048;      // 4*16*64*2048
  unsigned short* attnb = vTb   + (long)4 * 16 * 64 * TB; // 8192*1024

  cvt_kernel<<<3072, 256, 0, stream>>>(
      (const float4*)x, (const float4*)wqkv, (const float4*)wout,
      (ushort4*)xb, (ushort4*)wqkvb, (ushort4*)woutb);

  // QKV projection: 256x128 tiles, 768 blocks (reverted to r7/r8 best)
  gemm_qkv<<<dim3(24, 32), 512, 0, stream>>>(xb, wqkvb, EMB, qkb, vTb);

  attn_kernel<<<dim3(64, 16), 256, 0, stream>>>(qkb, vTb, attnb);

  // output projection: 128x64 tiles, 1024 blocks (frozen from r8)
  gemm_out<<<dim3(16, 64), 256, 0, stream>>>(attnb, woutb, EMB, outp);
}